// Round 1
// baseline (2879.147 us; speedup 1.0000x reference)
//
#include <hip/hip_runtime.h>
#include <stdint.h>

// RNN_6725918786207: 2-layer tanh RNN. B=64, T=512, D_IN=64, D_MODEL=512, D_OUT=64.
// Phased plan:
//   1. prep: cast/pack weights to fp16 (Whh -> pair-packed for v_dot2; Wih/Wout -> transposed [N][K])
//   2. X0 = data@Wih0 + (bih0+bhh0)                (MFMA f16 GEMM, fp16 out)
//   3. rnn0: h0_t = tanh(X0_t + h0@Whh0)           (64 WGs, 1/batch, Whh regs+LDS resident)
//   4. X1 = H0@Wih1 + (bih1+bhh1)                  (MFMA GEMM)
//   5. rnn1: h1_t = tanh(X1_t + h1@Whh1)
//   6. OUT = H1@Wout + bout  -> d_out fp32
// Workspace requirement: ~101.7 MiB (asserted by construction; see offsets below).

typedef unsigned int u32;
typedef unsigned short u16;
typedef _Float16 f16;
typedef _Float16 h2  __attribute__((ext_vector_type(2)));
typedef _Float16 v8h __attribute__((ext_vector_type(8)));
typedef float    v4f __attribute__((ext_vector_type(4)));

#define T_STEPS 512
#define DM 512      // d_model
#define BATCH 64

// ---------- small helpers ----------
__device__ __forceinline__ float f16lo(u32 u) {
    u16 s = (u16)(u & 0xffffu); f16 h; __builtin_memcpy(&h, &s, 2); return (float)h;
}
__device__ __forceinline__ float f16hi(u32 u) {
    u16 s = (u16)(u >> 16); f16 h; __builtin_memcpy(&h, &s, 2); return (float)h;
}
__device__ __forceinline__ u32 packh2(float lo, float hi) {
    f16 a = (f16)lo, b = (f16)hi; u16 ua, ub;
    __builtin_memcpy(&ua, &a, 2); __builtin_memcpy(&ub, &b, 2);
    return (u32)ua | ((u32)ub << 16);
}
__device__ __forceinline__ float fdot2u(u32 w, u32 h, float acc) {
    h2 a, b; __builtin_memcpy(&a, &w, 4); __builtin_memcpy(&b, &h, 4);
    return __builtin_amdgcn_fdot2(a, b, acc, false);
}
__device__ __forceinline__ u32 RL(u32 v, int l) {
    return (u32)__builtin_amdgcn_readlane((int)v, l);
}
__device__ __forceinline__ float tanh_fast(float z) {
    // tanh(z) = 1 - 2/(exp(2z)+1); exp inf/0 endpoints saturate correctly.
    float e = __expf(2.0f * z);
    return 1.0f - 2.0f / (e + 1.0f);
}

// ---------- prep kernels ----------
__global__ void k_cast_f16(const float* __restrict__ src, f16* __restrict__ dst, int n) {
    int i = blockIdx.x * blockDim.x + threadIdx.x;
    if (i < n) dst[i] = (f16)src[i];
}

// W [512][512] fp32 row-major (k-major) -> Wp [256 pair-rows][256 col-pairs] of uint2:
//   Wp[p][c].x = pack(W[2p][2c],   W[2p+1][2c])
//   Wp[p][c].y = pack(W[2p][2c+1], W[2p+1][2c+1])
__global__ void k_pack_whh(const float* __restrict__ W, uint2* __restrict__ Wp) {
    int i = blockIdx.x * blockDim.x + threadIdx.x;  // 65536
    int p = i >> 8, c = i & 255;
    int k0 = 2 * p, j0 = 2 * c;
    uint2 o;
    o.x = packh2(W[k0 * DM + j0],     W[(k0 + 1) * DM + j0]);
    o.y = packh2(W[k0 * DM + j0 + 1], W[(k0 + 1) * DM + j0 + 1]);
    Wp[p * 256 + c] = o;
}

// src fp32 [R][C] -> dst fp16 [C][R]
__global__ void k_transpose_f16(const float* __restrict__ src, f16* __restrict__ dst, int R, int C) {
    int i = blockIdx.x * blockDim.x + threadIdx.x;
    if (i < R * C) { int r = i / C, c = i % C; dst[c * R + r] = (f16)src[r * C + c]; }
}

__global__ void k_bias_sum(const float* a0, const float* b0, float* o0,
                           const float* a1, const float* b1, float* o1) {
    int i = blockIdx.x * blockDim.x + threadIdx.x;
    if (i < DM) { o0[i] = a0[i] + b0[i]; o1[i] = a1[i] + b1[i]; }
}

// ---------- MFMA f16 GEMM: C[M][N] = A[M][K] @ B[K][N] + bias, B given transposed BT[N][K].
// Tile 64x64, 256 threads (4 waves; wave w owns m-rows [16w,16w+16)).
__global__ __launch_bounds__(256) void k_gemm(const f16* __restrict__ A, const f16* __restrict__ BT,
                                              void* __restrict__ Cout, const float* __restrict__ bias,
                                              int M, int N, int K, int out_f32) {
    __shared__ f16 As[64][40];  // [m][k] padded
    __shared__ f16 Bs[64][40];  // [n][k] padded
    int tid = threadIdx.x;
    int mb = blockIdx.x, nb = blockIdx.y;
    int l = tid & 63, w = tid >> 6;
    int q = l >> 4, mr = l & 15;

    int sr = tid >> 2;            // staging row 0..63
    int ko = (tid & 3) * 8;       // staging k-offset (f16 units)
    const f16* gA = A + (size_t)(mb * 64 + sr) * K + ko;
    const f16* gB = BT + (size_t)(nb * 64 + sr) * K + ko;

    v4f acc[4];
    #pragma unroll
    for (int nt = 0; nt < 4; ++nt) acc[nt] = (v4f){0.f, 0.f, 0.f, 0.f};

    for (int kt = 0; kt < K; kt += 32) {
        *(uint4*)&As[sr][ko] = *(const uint4*)(gA + kt);
        *(uint4*)&Bs[sr][ko] = *(const uint4*)(gB + kt);
        __syncthreads();
        v8h a = *(const v8h*)&As[w * 16 + mr][q * 8];
        #pragma unroll
        for (int nt = 0; nt < 4; ++nt) {
            v8h b = *(const v8h*)&Bs[nt * 16 + mr][q * 8];
            acc[nt] = __builtin_amdgcn_mfma_f32_16x16x32_f16(a, b, acc[nt], 0, 0, 0);
        }
        __syncthreads();
    }

    int row0 = mb * 64 + w * 16 + q * 4;
    #pragma unroll
    for (int nt = 0; nt < 4; ++nt) {
        int col = nb * 64 + nt * 16 + mr;
        float bv = bias[col];
        #pragma unroll
        for (int r = 0; r < 4; ++r) {
            float v = acc[nt][r] + bv;
            if (out_f32) ((float*)Cout)[(size_t)(row0 + r) * N + col] = v;
            else         ((f16*)Cout)[(size_t)(row0 + r) * N + col] = (f16)v;
        }
    }
}

// ---------- recurrence kernel ----------
// One WG per batch element. 256 threads (4 waves). Thread c owns cols 2c, 2c+1.
// Whh packed as Wp[256 pair-rows][256 col-pairs] uint2. Pairs p=0..191 live in VGPRs,
// pairs 192..255 live in LDS (uint4 = 2 pair-rows x 2 cols). h broadcast via readlane.
__global__ __launch_bounds__(256, 1) void k_rnn(const u32* __restrict__ X,   // [B*T][256] f16-pairs
                                                const uint2* __restrict__ Wp,
                                                u32* __restrict__ H) {       // [B*T][256] f16-pairs
    __shared__ uint4 ldsW[32 * 256];   // 128 KiB: pairs 192..255
    __shared__ u32 hbuf[2][256];       // double-buffered h (f16 pairs)

    int b = blockIdx.x, tid = threadIdx.x, lane = tid & 63;

    // stage LDS-resident part of W
    for (int i = tid; i < 32 * 256; i += 256) {
        int q2 = i >> 8, c = i & 255;
        uint2 lo = Wp[(192 + 2 * q2) * 256 + c];
        uint2 hi = Wp[(193 + 2 * q2) * 256 + c];
        ldsW[i] = make_uint4(lo.x, lo.y, hi.x, hi.y);
    }

    // register-resident part of W: 384 VGPRs
    u32 w0[192], w1[192];
    #pragma unroll
    for (int p = 0; p < 192; ++p) {
        uint2 t = Wp[p * 256 + tid];
        w0[p] = t.x; w1[p] = t.y;
    }

    hbuf[0][tid] = 0u;  // h_0 = 0
    __syncthreads();

    const u32* Xb = X + (size_t)b * T_STEPS * 256;
    u32* Hb = H + (size_t)b * T_STEPS * 256;
    int cur = 0;

    for (int t = 0; t < T_STEPS; ++t) {
        u32 hr[4];
        #pragma unroll
        for (int r = 0; r < 4; ++r) hr[r] = hbuf[cur][r * 64 + lane];
        u32 xv = Xb[t * 256 + tid];   // issued early, consumed at the end

        float a0 = 0.f, a1 = 0.f, a2 = 0.f, a3 = 0.f;  // 4 chains for ILP
        #pragma unroll
        for (int p = 0; p < 192; p += 2) {
            u32 hA = RL(hr[p >> 6], p & 63);
            u32 hB = RL(hr[(p + 1) >> 6], (p + 1) & 63);
            a0 = fdot2u(w0[p], hA, a0);
            a1 = fdot2u(w1[p], hA, a1);
            a2 = fdot2u(w0[p + 1], hB, a2);
            a3 = fdot2u(w1[p + 1], hB, a3);
        }
        #pragma unroll
        for (int q2 = 0; q2 < 32; ++q2) {
            uint4 wv = ldsW[q2 * 256 + tid];
            int p0 = 192 + 2 * q2;                 // p0>>6 == 3
            u32 hA = RL(hr[3], p0 & 63);
            u32 hB = RL(hr[3], (p0 + 1) & 63);
            a0 = fdot2u(wv.x, hA, a0);
            a1 = fdot2u(wv.y, hA, a1);
            a2 = fdot2u(wv.z, hB, a2);
            a3 = fdot2u(wv.w, hB, a3);
        }

        float y0 = a0 + a2 + f16lo(xv);
        float y1 = a1 + a3 + f16hi(xv);
        u32 hp = packh2(tanh_fast(y0), tanh_fast(y1));
        hbuf[cur ^ 1][tid] = hp;
        Hb[t * 256 + tid] = hp;
        __syncthreads();
        cur ^= 1;
    }
}

// ---------- launch ----------
extern "C" void kernel_launch(void* const* d_in, const int* in_sizes, int n_in,
                              void* d_out, int out_size, void* d_ws, size_t ws_size,
                              hipStream_t stream) {
    (void)in_sizes; (void)n_in; (void)out_size; (void)ws_size;
    const float* data = (const float*)d_in[0];
    const float* Wih0 = (const float*)d_in[1];
    const float* bih0 = (const float*)d_in[2];
    const float* Whh0 = (const float*)d_in[3];
    const float* bhh0 = (const float*)d_in[4];
    const float* Wih1 = (const float*)d_in[5];
    const float* bih1 = (const float*)d_in[6];
    const float* Whh1 = (const float*)d_in[7];
    const float* bhh1 = (const float*)d_in[8];
    const float* Wout = (const float*)d_in[9];
    const float* bout = (const float*)d_in[10];

    char* ws = (char*)d_ws;
    // workspace layout (bytes); total = 106,565,632 (~101.7 MiB)
    f16*   X    = (f16*)(ws + 0);                    // [32768][512] f16 (shared X0/X1)
    f16*   H0   = (f16*)(ws + 33554432);             // [32768][512] f16
    f16*   H1   = (f16*)(ws + 67108864);             // [32768][512] f16
    f16*   D16  = (f16*)(ws + 100663296);            // data fp16 [32768][64]
    uint2* Wp0  = (uint2*)(ws + 104857600);          // packed Whh0
    uint2* Wp1  = (uint2*)(ws + 105381888);          // packed Whh1
    f16*   WT0  = (f16*)(ws + 105906176);            // Wih0^T [512][64]
    f16*   WT1  = (f16*)(ws + 105971712);            // Wih1^T [512][512]
    f16*   WoT  = (f16*)(ws + 106496000);            // Wout^T [64][512]
    float* bias0 = (float*)(ws + 106561536);
    float* bias1 = (float*)(ws + 106563584);

    // prep
    k_cast_f16<<<8192, 256, 0, stream>>>(data, D16, 64 * 512 * 64);
    k_pack_whh<<<256, 256, 0, stream>>>(Whh0, Wp0);
    k_pack_whh<<<256, 256, 0, stream>>>(Whh1, Wp1);
    k_transpose_f16<<<128, 256, 0, stream>>>(Wih0, WT0, 64, 512);
    k_transpose_f16<<<1024, 256, 0, stream>>>(Wih1, WT1, 512, 512);
    k_transpose_f16<<<128, 256, 0, stream>>>(Wout, WoT, 512, 64);
    k_bias_sum<<<2, 256, 0, stream>>>(bih0, bhh0, bias0, bih1, bhh1, bias1);

    dim3 gX(512, 8), gO(512, 1);
    // X0 = data @ Wih0 + bias0
    k_gemm<<<gX, 256, 0, stream>>>(D16, WT0, (void*)X, bias0, 32768, 512, 64, 0);
    // layer-0 recurrence
    k_rnn<<<64, 256, 0, stream>>>((const u32*)X, Wp0, (u32*)H0);
    // X1 = H0 @ Wih1 + bias1
    k_gemm<<<gX, 256, 0, stream>>>(H0, WT1, (void*)X, bias1, 32768, 512, 512, 0);
    // layer-1 recurrence
    k_rnn<<<64, 256, 0, stream>>>((const u32*)X, Wp1, (u32*)H1);
    // OUT = H1 @ Wout + bout -> fp32 d_out
    k_gemm<<<gO, 256, 0, stream>>>(H1, WoT, d_out, bout, 32768, 64, 512, 1);
}

// Round 2
// 2372.599 us; speedup vs baseline: 1.2135x; 1.2135x over previous
//
#include <hip/hip_runtime.h>
#include <stdint.h>

// RNN_6725918786207: 2-layer tanh RNN. B=64, T=512, D_IN=64, D_MODEL=512, D_OUT=64.
// Round 2: k_rnn weights truly resident — w0 pinned in ArchVGPRs (volatile v_mov),
// w1 in AGPRs (v_accvgpr_write once, v_accvgpr_read per step). Round 1 showed the
// compiler re-fetched weights from L2 every step (ArchVGPR cap = 256, demand was 384).

typedef unsigned int u32;
typedef unsigned short u16;
typedef _Float16 f16;
typedef _Float16 h2  __attribute__((ext_vector_type(2)));
typedef _Float16 v8h __attribute__((ext_vector_type(8)));
typedef float    v4f __attribute__((ext_vector_type(4)));

#define T_STEPS 512
#define DM 512      // d_model
#define BATCH 64

// ---------- small helpers ----------
__device__ __forceinline__ float f16lo(u32 u) {
    u16 s = (u16)(u & 0xffffu); f16 h; __builtin_memcpy(&h, &s, 2); return (float)h;
}
__device__ __forceinline__ float f16hi(u32 u) {
    u16 s = (u16)(u >> 16); f16 h; __builtin_memcpy(&h, &s, 2); return (float)h;
}
__device__ __forceinline__ u32 packh2(float lo, float hi) {
    f16 a = (f16)lo, b = (f16)hi; u16 ua, ub;
    __builtin_memcpy(&ua, &a, 2); __builtin_memcpy(&ub, &b, 2);
    return (u32)ua | ((u32)ub << 16);
}
__device__ __forceinline__ float fdot2u(u32 w, u32 h, float acc) {
    h2 a, b; __builtin_memcpy(&a, &w, 4); __builtin_memcpy(&b, &h, 4);
    return __builtin_amdgcn_fdot2(a, b, acc, false);
}
__device__ __forceinline__ u32 RL(u32 v, int l) {
    return (u32)__builtin_amdgcn_readlane((int)v, l);
}
__device__ __forceinline__ float tanh_fast(float z) {
    float e = __expf(2.0f * z);
    return 1.0f - 2.0f / (e + 1.0f);
}

// ---------- prep kernels ----------
__global__ void k_cast_f16(const float* __restrict__ src, f16* __restrict__ dst, int n) {
    int i = blockIdx.x * blockDim.x + threadIdx.x;
    if (i < n) dst[i] = (f16)src[i];
}

// W [512][512] fp32 row-major (k-major) -> Wp [256 pair-rows][256 col-pairs] of uint2:
//   Wp[p][c].x = pack(W[2p][2c],   W[2p+1][2c])
//   Wp[p][c].y = pack(W[2p][2c+1], W[2p+1][2c+1])
__global__ void k_pack_whh(const float* __restrict__ W, uint2* __restrict__ Wp) {
    int i = blockIdx.x * blockDim.x + threadIdx.x;  // 65536
    int p = i >> 8, c = i & 255;
    int k0 = 2 * p, j0 = 2 * c;
    uint2 o;
    o.x = packh2(W[k0 * DM + j0],     W[(k0 + 1) * DM + j0]);
    o.y = packh2(W[k0 * DM + j0 + 1], W[(k0 + 1) * DM + j0 + 1]);
    Wp[p * 256 + c] = o;
}

// src fp32 [R][C] -> dst fp16 [C][R]
__global__ void k_transpose_f16(const float* __restrict__ src, f16* __restrict__ dst, int R, int C) {
    int i = blockIdx.x * blockDim.x + threadIdx.x;
    if (i < R * C) { int r = i / C, c = i % C; dst[c * R + r] = (f16)src[r * C + c]; }
}

__global__ void k_bias_sum(const float* a0, const float* b0, float* o0,
                           const float* a1, const float* b1, float* o1) {
    int i = blockIdx.x * blockDim.x + threadIdx.x;
    if (i < DM) { o0[i] = a0[i] + b0[i]; o1[i] = a1[i] + b1[i]; }
}

// ---------- MFMA f16 GEMM: C[M][N] = A[M][K] @ B[K][N] + bias, B given transposed BT[N][K].
// Tile 64x64, 256 threads (4 waves; wave w owns m-rows [16w,16w+16)).
__global__ __launch_bounds__(256) void k_gemm(const f16* __restrict__ A, const f16* __restrict__ BT,
                                              void* __restrict__ Cout, const float* __restrict__ bias,
                                              int M, int N, int K, int out_f32) {
    __shared__ f16 As[64][40];  // [m][k] padded
    __shared__ f16 Bs[64][40];  // [n][k] padded
    int tid = threadIdx.x;
    int mb = blockIdx.x, nb = blockIdx.y;
    int l = tid & 63, w = tid >> 6;
    int q = l >> 4, mr = l & 15;

    int sr = tid >> 2;            // staging row 0..63
    int ko = (tid & 3) * 8;       // staging k-offset (f16 units)
    const f16* gA = A + (size_t)(mb * 64 + sr) * K + ko;
    const f16* gB = BT + (size_t)(nb * 64 + sr) * K + ko;

    v4f acc[4];
    #pragma unroll
    for (int nt = 0; nt < 4; ++nt) acc[nt] = (v4f){0.f, 0.f, 0.f, 0.f};

    for (int kt = 0; kt < K; kt += 32) {
        *(uint4*)&As[sr][ko] = *(const uint4*)(gA + kt);
        *(uint4*)&Bs[sr][ko] = *(const uint4*)(gB + kt);
        __syncthreads();
        v8h a = *(const v8h*)&As[w * 16 + mr][q * 8];
        #pragma unroll
        for (int nt = 0; nt < 4; ++nt) {
            v8h b = *(const v8h*)&Bs[nt * 16 + mr][q * 8];
            acc[nt] = __builtin_amdgcn_mfma_f32_16x16x32_f16(a, b, acc[nt], 0, 0, 0);
        }
        __syncthreads();
    }

    int row0 = mb * 64 + w * 16 + q * 4;
    #pragma unroll
    for (int nt = 0; nt < 4; ++nt) {
        int col = nb * 64 + nt * 16 + mr;
        float bv = bias[col];
        #pragma unroll
        for (int r = 0; r < 4; ++r) {
            float v = acc[nt][r] + bv;
            if (out_f32) ((float*)Cout)[(size_t)(row0 + r) * N + col] = v;
            else         ((f16*)Cout)[(size_t)(row0 + r) * N + col] = (f16)v;
        }
    }
}

// ---------- recurrence kernel ----------
// One WG per batch element. 256 threads (4 waves). Thread c owns cols 2c, 2c+1.
// Whh packed as Wp[256 pair-rows][256 col-pairs] uint2. Pair-rows 0..191:
//   col 2c   -> w0[p]  pinned in ArchVGPRs (volatile v_mov)
//   col 2c+1 -> w1a[p] stashed in AGPRs (v_accvgpr_write / read)
// Pair-rows 192..255 live in LDS (uint4 = 2 pair-rows x 2 cols).
// h broadcast via readlane; fp32 accumulation in 4 chains.
__global__ __launch_bounds__(256, 1) void k_rnn(const u32* __restrict__ X,   // [B*T][256] f16-pairs
                                                const uint2* __restrict__ Wp,
                                                u32* __restrict__ H) {       // [B*T][256] f16-pairs
    __shared__ uint4 ldsW[32 * 256];   // 128 KiB: pair-rows 192..255
    __shared__ u32 hbuf[2][256];       // double-buffered h (f16 pairs)

    int b = blockIdx.x, tid = threadIdx.x, lane = tid & 63;

    // stage LDS-resident part of W
    for (int i = tid; i < 32 * 256; i += 256) {
        int q2 = i >> 8, c = i & 255;
        uint2 lo = Wp[(192 + 2 * q2) * 256 + c];
        uint2 hi = Wp[(193 + 2 * q2) * 256 + c];
        ldsW[i] = make_uint4(lo.x, lo.y, hi.x, hi.y);
    }

    // register-resident part of W: 192 ArchVGPRs (w0) + 192 AGPRs (w1a)
    u32 w0[192];
    u32 w1a[192];
    #pragma unroll
    for (int p = 0; p < 192; ++p) {
        uint2 t = Wp[p * 256 + tid];
        asm volatile("v_mov_b32 %0, %1" : "=v"(w0[p]) : "v"(t.x));
        asm volatile("v_accvgpr_write_b32 %0, %1" : "=a"(w1a[p]) : "v"(t.y));
    }

    hbuf[0][tid] = 0u;  // h_0 = 0
    __syncthreads();

    const u32* Xb = X + (size_t)b * T_STEPS * 256;
    u32* Hb = H + (size_t)b * T_STEPS * 256;
    int cur = 0;

    for (int t = 0; t < T_STEPS; ++t) {
        u32 hr[4];
        #pragma unroll
        for (int r = 0; r < 4; ++r) hr[r] = hbuf[cur][r * 64 + lane];
        u32 xv = Xb[t * 256 + tid];   // issued early, consumed at the end

        float a0 = 0.f, a1 = 0.f, a2 = 0.f, a3 = 0.f;  // 4 chains for ILP
        #pragma unroll
        for (int p = 0; p < 192; p += 2) {
            u32 hA = RL(hr[p >> 6], p & 63);
            u32 hB = RL(hr[(p + 1) >> 6], (p + 1) & 63);
            u32 y0, y1;
            asm volatile("v_accvgpr_read_b32 %0, %1" : "=v"(y0) : "a"(w1a[p]));
            asm volatile("v_accvgpr_read_b32 %0, %1" : "=v"(y1) : "a"(w1a[p + 1]));
            a0 = fdot2u(w0[p], hA, a0);
            a1 = fdot2u(y0, hA, a1);
            a2 = fdot2u(w0[p + 1], hB, a2);
            a3 = fdot2u(y1, hB, a3);
        }
        #pragma unroll
        for (int q2 = 0; q2 < 32; ++q2) {
            uint4 wv = ldsW[q2 * 256 + tid];
            int p0 = 192 + 2 * q2;                 // p0>>6 == 3
            u32 hA = RL(hr[3], p0 & 63);
            u32 hB = RL(hr[3], (p0 + 1) & 63);
            a0 = fdot2u(wv.x, hA, a0);
            a1 = fdot2u(wv.y, hA, a1);
            a2 = fdot2u(wv.z, hB, a2);
            a3 = fdot2u(wv.w, hB, a3);
        }

        float y0 = a0 + f16lo(xv);
        float y1 = a1 + f16hi(xv);
        // note: a0/a2 are lo-col partials, a1/a3 are hi-col partials
        float z0 = y0 + a2;
        float z1 = y1 + a3;
        u32 hp = packh2(tanh_fast(z0), tanh_fast(z1));
        hbuf[cur ^ 1][tid] = hp;
        Hb[t * 256 + tid] = hp;
        __syncthreads();
        cur ^= 1;
    }
}

// ---------- launch ----------
extern "C" void kernel_launch(void* const* d_in, const int* in_sizes, int n_in,
                              void* d_out, int out_size, void* d_ws, size_t ws_size,
                              hipStream_t stream) {
    (void)in_sizes; (void)n_in; (void)out_size; (void)ws_size;
    const float* data = (const float*)d_in[0];
    const float* Wih0 = (const float*)d_in[1];
    const float* bih0 = (const float*)d_in[2];
    const float* Whh0 = (const float*)d_in[3];
    const float* bhh0 = (const float*)d_in[4];
    const float* Wih1 = (const float*)d_in[5];
    const float* bih1 = (const float*)d_in[6];
    const float* Whh1 = (const float*)d_in[7];
    const float* bhh1 = (const float*)d_in[8];
    const float* Wout = (const float*)d_in[9];
    const float* bout = (const float*)d_in[10];

    char* ws = (char*)d_ws;
    // workspace layout (bytes); total = 106,565,632 (~101.7 MiB)
    f16*   X    = (f16*)(ws + 0);                    // [32768][512] f16 (shared X0/X1)
    f16*   H0   = (f16*)(ws + 33554432);             // [32768][512] f16
    f16*   H1   = (f16*)(ws + 67108864);             // [32768][512] f16
    f16*   D16  = (f16*)(ws + 100663296);            // data fp16 [32768][64]
    uint2* Wp0  = (uint2*)(ws + 104857600);          // packed Whh0
    uint2* Wp1  = (uint2*)(ws + 105381888);          // packed Whh1
    f16*   WT0  = (f16*)(ws + 105906176);            // Wih0^T [512][64]
    f16*   WT1  = (f16*)(ws + 105971712);            // Wih1^T [512][512]
    f16*   WoT  = (f16*)(ws + 106496000);            // Wout^T [64][512]
    float* bias0 = (float*)(ws + 106561536);
    float* bias1 = (float*)(ws + 106563584);

    // prep
    k_cast_f16<<<8192, 256, 0, stream>>>(data, D16, 64 * 512 * 64);
    k_pack_whh<<<256, 256, 0, stream>>>(Whh0, Wp0);
    k_pack_whh<<<256, 256, 0, stream>>>(Whh1, Wp1);
    k_transpose_f16<<<128, 256, 0, stream>>>(Wih0, WT0, 64, 512);
    k_transpose_f16<<<1024, 256, 0, stream>>>(Wih1, WT1, 512, 512);
    k_transpose_f16<<<128, 256, 0, stream>>>(Wout, WoT, 512, 64);
    k_bias_sum<<<2, 256, 0, stream>>>(bih0, bhh0, bias0, bih1, bhh1, bias1);

    dim3 gX(512, 8), gO(512, 1);
    // X0 = data @ Wih0 + bias0
    k_gemm<<<gX, 256, 0, stream>>>(D16, WT0, (void*)X, bias0, 32768, 512, 64, 0);
    // layer-0 recurrence
    k_rnn<<<64, 256, 0, stream>>>((const u32*)X, Wp0, (u32*)H0);
    // X1 = H0 @ Wih1 + bias1
    k_gemm<<<gX, 256, 0, stream>>>(H0, WT1, (void*)X, bias1, 32768, 512, 512, 0);
    // layer-1 recurrence
    k_rnn<<<64, 256, 0, stream>>>((const u32*)X, Wp1, (u32*)H1);
    // OUT = H1 @ Wout + bout -> fp32 d_out
    k_gemm<<<gO, 256, 0, stream>>>(H1, WoT, d_out, bout, 32768, 64, 512, 1);
}